// Round 1
// baseline (937.757 us; speedup 1.0000x reference)
//
#include <hip/hip_runtime.h>

#define LOG2E 1.44269504088896f

typedef __attribute__((ext_vector_type(8))) short bf8v;
typedef __attribute__((ext_vector_type(16))) float f16v;

union B8 { bf8v v; short s[8]; unsigned u[4]; uint2 d[2]; uint4 q; };
union F16 { f16v v; float f[16]; };

__device__ __forceinline__ unsigned short f2bf(float f) {
    union { float f; unsigned u; } c; c.f = f;
    unsigned r = c.u + 0x7FFFu + ((c.u >> 16) & 1u);
    return (unsigned short)(r >> 16);
}
__device__ __forceinline__ unsigned pk2(float a, float b) {
    return (unsigned)f2bf(a) | ((unsigned)f2bf(b) << 16);
}
__device__ __forceinline__ int rowpat(int reg, int half) {
    return (reg & 3) + 8 * (reg >> 2) + 4 * half;
}

// ---------------- LayerNorm over last dim = 128, one wave per row ----------------
__global__ __launch_bounds__(64) void ln_kernel(const float* __restrict__ x,
                                                const float* __restrict__ g,
                                                const float* __restrict__ b,
                                                float* __restrict__ y) {
    int row = blockIdx.x;
    int lane = threadIdx.x;
    const float* xr = x + (size_t)row * 128;
    float2 v = *(const float2*)(xr + lane * 2);
    float s = v.x + v.y;
    float sq = v.x * v.x + v.y * v.y;
    #pragma unroll
    for (int o = 32; o > 0; o >>= 1) { s += __shfl_xor(s, o); sq += __shfl_xor(sq, o); }
    float m = s * (1.f / 128.f);
    float var = sq * (1.f / 128.f) - m * m;
    float r = rsqrtf(fmaxf(var, 0.f) + 1e-5f);
    float2 gg = *(const float2*)(g + lane * 2);
    float2 bb = *(const float2*)(b + lane * 2);
    float2 o2;
    o2.x = (v.x - m) * r * gg.x + bb.x;
    o2.y = (v.y - m) * r * gg.y + bb.y;
    *(float2*)(y + (size_t)row * 128 + lane * 2) = o2;
}

// ---------------- Generic GEMM: out[M,N] = A[M,K] @ W[N,K]^T (+bias, relu, +res) -------
// block 256 = 4 waves, each wave one 32x32 output tile. grid(M/128, N/32)
__global__ __launch_bounds__(256) void gemm_kernel(const float* __restrict__ A,
                                                   const float* __restrict__ W,
                                                   const float* __restrict__ bias,
                                                   float* __restrict__ out,
                                                   const float* __restrict__ res,
                                                   int K, int ldo, int mode) {
    int t = threadIdx.x, w = t >> 6, lane = t & 63;
    int lm = lane & 31, half = lane >> 5;
    int row0 = blockIdx.x * 128 + w * 32;
    int col0 = blockIdx.y * 32;
    const float* ap = A + (size_t)(row0 + lm) * K + half * 8;
    const float* wp = W + (size_t)(col0 + lm) * K + half * 8;
    F16 acc;
    #pragma unroll
    for (int i = 0; i < 16; i++) acc.f[i] = 0.f;
    for (int k0 = 0; k0 < K; k0 += 16) {
        float4 a0 = *(const float4*)(ap + k0);
        float4 a1 = *(const float4*)(ap + k0 + 4);
        float4 w0 = *(const float4*)(wp + k0);
        float4 w1 = *(const float4*)(wp + k0 + 4);
        B8 af, wf;
        af.u[0] = pk2(a0.x, a0.y); af.u[1] = pk2(a0.z, a0.w);
        af.u[2] = pk2(a1.x, a1.y); af.u[3] = pk2(a1.z, a1.w);
        wf.u[0] = pk2(w0.x, w0.y); wf.u[1] = pk2(w0.z, w0.w);
        wf.u[2] = pk2(w1.x, w1.y); wf.u[3] = pk2(w1.z, w1.w);
        acc.v = __builtin_amdgcn_mfma_f32_32x32x16_bf16(af.v, wf.v, acc.v, 0, 0, 0);
    }
    float bv = bias ? bias[col0 + lm] : 0.f;
    int col = col0 + lm;
    #pragma unroll
    for (int reg = 0; reg < 16; reg++) {
        int row = row0 + rowpat(reg, half);
        float v = acc.f[reg] + bv;
        if (mode == 1) v = fmaxf(v, 0.f);
        if (mode == 2) v += res[(size_t)row * ldo + col];
        out[(size_t)row * ldo + col] = v;
    }
}

// ---------------- Fused edge-MLP + masked attention (flash-style) ----------------
// grid(b=8, itile=32), block 512 = 8 waves, wave w = head w. Ti=Tj=32.
__global__ __launch_bounds__(512) void attn_kernel(
    const float* __restrict__ Qm, const float* __restrict__ Km, const float* __restrict__ Vm,
    const float* __restrict__ xp, const float* __restrict__ ea, const int* __restrict__ adj,
    const float* __restrict__ We1, const float* __restrict__ be1,
    const float* __restrict__ We2, const float* __restrict__ be2,
    const float* __restrict__ eg, const float* __restrict__ eb,
    float* __restrict__ ha) {
    __shared__ short smK[32][132];      // bf16 K-tile [tj][f]
    __shared__ short smVt[128][36];     // bf16 V-tile transposed [f][tj]
    __shared__ float smBias[8480];      // [tj]*265 + h*33 + ti   (masked bias)
    __shared__ short smH1[8][1280];     // per-wave h1 transpose scratch [edge][ch], stride 40

    int b = blockIdx.x, i0 = blockIdx.y * 32;
    int t = threadIdx.x, w = t >> 6;
    int lane = t & 63, lm = lane & 31, half = lane >> 5;

    // ---- per-lane constant fragments ----
    B8 qf, w1f, w2a, w2b;
    {   // B-frag Q^T for head w: n = ti = lm, k = d = half*8+j  (pre-scaled 1/sqrt(16))
        const float* qp = Qm + (size_t)(b * 1024 + i0 + lm) * 128 + w * 16 + half * 8;
        float4 q0 = *(const float4*)qp, q1 = *(const float4*)(qp + 4);
        qf.u[0] = pk2(q0.x * 0.25f, q0.y * 0.25f); qf.u[1] = pk2(q0.z * 0.25f, q0.w * 0.25f);
        qf.u[2] = pk2(q1.x * 0.25f, q1.y * 0.25f); qf.u[3] = pk2(q1.z * 0.25f, q1.w * 0.25f);
    }
    {   // A-frag We1*gamma: m = ch = lm, k = feat = half*8+j
        const float* wp = We1 + lm * 16 + half * 8;
        #pragma unroll
        for (int j = 0; j < 8; j++) w1f.s[j] = (short)f2bf(wp[j] * eg[half * 8 + j]);
    }
    {   // A-frags We2 (M rows 8..31 are don't-care): m = h = lm&7
        int hs = lm & 7;
        #pragma unroll
        for (int j = 0; j < 8; j++) {
            w2a.s[j] = (short)f2bf(We2[hs * 32 + half * 8 + j]);
            w2b.s[j] = (short)f2bf(We2[hs * 32 + 16 + half * 8 + j]);
        }
    }
    // c1[ch] = sum_j We1[ch][j]*beta[j] + be1[ch], at D1-row positions
    float c1r[16];
    #pragma unroll
    for (int reg = 0; reg < 16; reg++) {
        int ch = rowpat(reg, half);
        float sacc = be1[ch];
        const float* wr = We1 + ch * 16;
        #pragma unroll
        for (int j = 0; j < 16; j++) sacc += wr[j] * eb[j];
        c1r[reg] = sacc;
    }
    float be2r[4];
    #pragma unroll
    for (int r = 0; r < 4; r++) be2r[r] = be2[r + 4 * half];

    F16 ou;
    #pragma unroll
    for (int i = 0; i < 16; i++) ou.f[i] = 0.f;
    float mrun = -3.0e38f, lrun = 0.f;

    #pragma unroll 1
    for (int nj = 0; nj < 32; nj++) {
        int j0 = nj * 32;
        __syncthreads();
        // ---- stage K (bf16) and V^T (bf16) ----
        {
            int rr = t >> 4, fc = (t & 15) * 8;
            const float* kp = Km + (size_t)(b * 1024 + j0 + rr) * 128 + fc;
            float4 k0 = *(const float4*)kp, k1 = *(const float4*)(kp + 4);
            uint2 p0; p0.x = pk2(k0.x, k0.y); p0.y = pk2(k0.z, k0.w);
            uint2 p1; p1.x = pk2(k1.x, k1.y); p1.y = pk2(k1.z, k1.w);
            *(uint2*)&smK[rr][fc] = p0;
            *(uint2*)&smK[rr][fc + 4] = p1;
            const float* vp = Vm + (size_t)(b * 1024 + j0 + rr) * 128 + fc;
            float4 v0 = *(const float4*)vp, v1 = *(const float4*)(vp + 4);
            smVt[fc + 0][rr] = (short)f2bf(v0.x); smVt[fc + 1][rr] = (short)f2bf(v0.y);
            smVt[fc + 2][rr] = (short)f2bf(v0.z); smVt[fc + 3][rr] = (short)f2bf(v0.w);
            smVt[fc + 4][rr] = (short)f2bf(v1.x); smVt[fc + 5][rr] = (short)f2bf(v1.y);
            smVt[fc + 6][rr] = (short)f2bf(v1.z); smVt[fc + 7][rr] = (short)f2bf(v1.w);
        }
        // ---- edge MLP: 4 ti-rows per wave; lane edge = tj = lm ----
        short* hrow = &smH1[w][lm * 40];
        for (int s4 = 0; s4 < 4; s4++) {
            int ti = w * 4 + s4;
            const float* ep = ea + ((size_t)(b * 1024 + i0 + ti) * 1024 + j0 + lm) * 16 + half * 8;
            float4 e0 = *(const float4*)ep, e1 = *(const float4*)(ep + 4);
            float sum = e0.x + e0.y + e0.z + e0.w + e1.x + e1.y + e1.z + e1.w;
            float sq = e0.x * e0.x + e0.y * e0.y + e0.z * e0.z + e0.w * e0.w
                     + e1.x * e1.x + e1.y * e1.y + e1.z * e1.z + e1.w * e1.w;
            sum += __shfl_xor(sum, 32); sq += __shfl_xor(sq, 32);
            float mn = sum * 0.0625f;
            float rs = rsqrtf(fmaxf(sq * 0.0625f - mn * mn, 0.f) + 1e-5f);
            float mr = mn * rs;
            B8 ef;   // B-frag eN^T: n = edge = lm, k = feat
            ef.u[0] = pk2(e0.x * rs - mr, e0.y * rs - mr);
            ef.u[1] = pk2(e0.z * rs - mr, e0.w * rs - mr);
            ef.u[2] = pk2(e1.x * rs - mr, e1.y * rs - mr);
            ef.u[3] = pk2(e1.z * rs - mr, e1.w * rs - mr);
            F16 z;
            #pragma unroll
            for (int i = 0; i < 16; i++) z.f[i] = 0.f;
            F16 h1; h1.v = __builtin_amdgcn_mfma_f32_32x32x16_bf16(w1f.v, ef.v, z.v, 0, 0, 0);
            // relu(h1 + c1) -> LDS [edge][ch] (bf16), pairs of consecutive ch
            #pragma unroll
            for (int pr = 0; pr < 8; pr++) {
                int r0 = 2 * pr;
                int ch0 = rowpat(r0, half);
                float a0 = fmaxf(h1.f[r0] + c1r[r0], 0.f);
                float a1 = fmaxf(h1.f[r0 + 1] + c1r[r0 + 1], 0.f);
                *(unsigned*)(hrow + ch0) = pk2(a0, a1);
            }
            B8 hba, hbb;   // B-frags h1: n = edge = lm, k = ch (two K halves)
            hba.q = *(const uint4*)(hrow + half * 8);
            hbb.q = *(const uint4*)(hrow + 16 + half * 8);
            F16 b2; b2.v = __builtin_amdgcn_mfma_f32_32x32x16_bf16(w2a.v, hba.v, z.v, 0, 0, 0);
            b2.v = __builtin_amdgcn_mfma_f32_32x32x16_bf16(w2b.v, hbb.v, b2.v, 0, 0, 0);
            int aj = adj[(size_t)(b * 1024 + i0 + ti) * 1024 + j0 + lm];
            #pragma unroll
            for (int reg = 0; reg < 4; reg++) {   // D2 rows 0..7 = h, col = edge = tj
                float bvv = aj ? (b2.f[reg] + be2r[reg]) : -1.0e9f;
                smBias[lm * 265 + (reg + 4 * half) * 33 + ti] = bvv;
            }
        }
        __syncthreads();
        // ---- attention, head w: S = K·Q^T + bias, col = ti = lm, rows = tj ----
        F16 sc;
        #pragma unroll
        for (int reg = 0; reg < 16; reg++) {
            int tj = rowpat(reg, half);
            sc.f[reg] = smBias[tj * 265 + w * 33 + lm];
        }
        B8 kf;   // A-frag K: m = tj = lm, k = d
        {
            const short* kp2 = &smK[lm][w * 16 + half * 8];
            kf.d[0] = *(const uint2*)kp2; kf.d[1] = *(const uint2*)(kp2 + 4);
        }
        F16 s; s.v = __builtin_amdgcn_mfma_f32_32x32x16_bf16(kf.v, qf.v, sc.v, 0, 0, 0);
        float mx = -3.0e38f;
        #pragma unroll
        for (int reg = 0; reg < 16; reg++) {
            float vv = s.f[reg];
            vv = fmaxf(vv, 0.2f * vv);   // LeakyReLU(0.2)
            s.f[reg] = vv;
            mx = fmaxf(mx, vv);
        }
        mx = fmaxf(mx, __shfl_xor(mx, 32));
        float mnew = fmaxf(mrun, mx);
        float al = exp2f((mrun - mnew) * LOG2E);
        float psum = 0.f;
        #pragma unroll
        for (int reg = 0; reg < 16; reg++) {
            float p = exp2f((s.f[reg] - mnew) * LOG2E);
            s.f[reg] = p; psum += p;
        }
        lrun = lrun * al + psum; mrun = mnew;
        // pack P and build A-frags (k = tj) via cross-half exchange
        unsigned q0 = pk2(s.f[0], s.f[1]), q0b = pk2(s.f[2], s.f[3]);
        unsigned q1 = pk2(s.f[4], s.f[5]), q1b = pk2(s.f[6], s.f[7]);
        unsigned q2 = pk2(s.f[8], s.f[9]), q2b = pk2(s.f[10], s.f[11]);
        unsigned q3 = pk2(s.f[12], s.f[13]), q3b = pk2(s.f[14], s.f[15]);
        unsigned x0 = __shfl_xor((int)q0, 32), x0b = __shfl_xor((int)q0b, 32);
        unsigned x1 = __shfl_xor((int)q1, 32), x1b = __shfl_xor((int)q1b, 32);
        unsigned x2 = __shfl_xor((int)q2, 32), x2b = __shfl_xor((int)q2b, 32);
        unsigned x3 = __shfl_xor((int)q3, 32), x3b = __shfl_xor((int)q3b, 32);
        B8 pfa, pfb;
        pfa.u[0] = half ? x1 : q0;  pfa.u[1] = half ? x1b : q0b;
        pfa.u[2] = half ? q1 : x0;  pfa.u[3] = half ? q1b : x0b;
        pfb.u[0] = half ? x3 : q2;  pfb.u[1] = half ? x3b : q2b;
        pfb.u[2] = half ? q3 : x2;  pfb.u[3] = half ? q3b : x2b;
        // rescale O by alpha (alpha for ti=r lives at lane r)
        #pragma unroll
        for (int reg = 0; reg < 16; reg++) {
            float av = __shfl(al, rowpat(reg, half));
            ou.f[reg] *= av;
        }
        int dcol = lm & 15;
        const short* vp2 = &smVt[w * 16 + dcol][half * 8];
        B8 vfa, vfb;   // B-frags V: n = d, k = tj
        vfa.d[0] = *(const uint2*)vp2;        vfa.d[1] = *(const uint2*)(vp2 + 4);
        vfb.d[0] = *(const uint2*)(vp2 + 16); vfb.d[1] = *(const uint2*)(vp2 + 20);
        ou.v = __builtin_amdgcn_mfma_f32_32x32x16_bf16(pfa.v, vfa.v, ou.v, 0, 0, 0);
        ou.v = __builtin_amdgcn_mfma_f32_32x32x16_bf16(pfb.v, vfb.v, ou.v, 0, 0, 0);
    }
    // ---- epilogue: h_attn = x_proj + O/l ----
    float ltot = lrun + __shfl_xor(lrun, 32);
    float linv = 1.f / ltot;
    int dcol = lm & 15;
    #pragma unroll
    for (int reg = 0; reg < 16; reg++) {
        int row = rowpat(reg, half);
        float lv = __shfl(linv, row);
        if (lm < 16) {
            size_t gi = (size_t)(b * 1024 + i0 + row) * 128 + w * 16 + dcol;
            ha[gi] = ou.f[reg] * lv + xp[gi];
        }
    }
}

extern "C" void kernel_launch(void* const* d_in, const int* in_sizes, int n_in,
                              void* d_out, int out_size, void* d_ws, size_t ws_size,
                              hipStream_t stream) {
    (void)in_sizes; (void)n_in; (void)out_size; (void)ws_size;
    const float* x    = (const float*)d_in[0];
    const int*   adj  = (const int*)d_in[1];
    const float* ea   = (const float*)d_in[2];
    const float* ln1g = (const float*)d_in[3];
    const float* ln1b = (const float*)d_in[4];
    const float* Wp   = (const float*)d_in[5];
    const float* bp   = (const float*)d_in[6];
    const float* eg   = (const float*)d_in[7];
    const float* eb   = (const float*)d_in[8];
    const float* We1  = (const float*)d_in[9];
    const float* be1  = (const float*)d_in[10];
    const float* We2  = (const float*)d_in[11];
    const float* be2  = (const float*)d_in[12];
    const float* Wq   = (const float*)d_in[13];
    const float* Wk   = (const float*)d_in[14];
    const float* Wv   = (const float*)d_in[15];
    const float* W1   = (const float*)d_in[16];
    const float* b1   = (const float*)d_in[17];
    const float* W2   = (const float*)d_in[18];
    const float* b2   = (const float*)d_in[19];
    const float* ln2g = (const float*)d_in[20];
    const float* ln2b = (const float*)d_in[21];
    float* out = (float*)d_out;
    float* ws = (float*)d_ws;

    const size_t M1 = (size_t)8 * 1024 * 128;
    float* xn    = ws;
    float* xproj = ws + 1 * M1;
    float* Qb    = ws + 2 * M1;
    float* Kb    = ws + 3 * M1;
    float* Vb    = ws + 4 * M1;
    float* haw   = ws + 5 * M1;
    float* hn    = ws + 6 * M1;
    float* h1b   = ws + 7 * M1;   // 8192 x 256

    ln_kernel<<<dim3(8192), dim3(64), 0, stream>>>(x, ln1g, ln1b, xn);
    gemm_kernel<<<dim3(64, 4), dim3(256), 0, stream>>>(xn, Wp, bp, xproj, nullptr, 128, 128, 0);
    gemm_kernel<<<dim3(64, 4), dim3(256), 0, stream>>>(xproj, Wq, nullptr, Qb, nullptr, 128, 128, 0);
    gemm_kernel<<<dim3(64, 4), dim3(256), 0, stream>>>(xproj, Wk, nullptr, Kb, nullptr, 128, 128, 0);
    gemm_kernel<<<dim3(64, 4), dim3(256), 0, stream>>>(xproj, Wv, nullptr, Vb, nullptr, 128, 128, 0);
    attn_kernel<<<dim3(8, 32), dim3(512), 0, stream>>>(Qb, Kb, Vb, xproj, ea, adj,
                                                       We1, be1, We2, be2, eg, eb, haw);
    ln_kernel<<<dim3(8192), dim3(64), 0, stream>>>(haw, ln2g, ln2b, hn);
    gemm_kernel<<<dim3(64, 8), dim3(256), 0, stream>>>(hn, W1, b1, h1b, nullptr, 128, 256, 1);
    gemm_kernel<<<dim3(64, 4), dim3(256), 0, stream>>>(h1b, W2, b2, out, haw, 256, 128, 2);
}

// Round 2
// 860.384 us; speedup vs baseline: 1.0899x; 1.0899x over previous
//
#include <hip/hip_runtime.h>

#define LOG2E 1.44269504088896f

typedef unsigned short u16;
typedef __attribute__((ext_vector_type(8))) short bf8v;
typedef __attribute__((ext_vector_type(16))) float f16v;

union B8 { bf8v v; short s[8]; unsigned u[4]; uint2 d[2]; uint4 q; };
union F16 { f16v v; float f[16]; };

__device__ __forceinline__ unsigned short f2bf(float f) {
    union { float f; unsigned u; } c; c.f = f;
    unsigned r = c.u + 0x7FFFu + ((c.u >> 16) & 1u);
    return (unsigned short)(r >> 16);
}
__device__ __forceinline__ unsigned pk2(float a, float b) {
#if __has_builtin(__builtin_amdgcn_cvt_pk_bf16_f32)
    typedef __attribute__((ext_vector_type(2))) __bf16 vbf2;
    union { vbf2 v; unsigned u; } c;
    c.v = __builtin_amdgcn_cvt_pk_bf16_f32(a, b);
    return c.u;
#else
    return (unsigned)f2bf(a) | ((unsigned)f2bf(b) << 16);
#endif
}
__device__ __forceinline__ u16 f2bf1(float a) { return (u16)(pk2(a, a) & 0xffffu); }
__device__ __forceinline__ int rowpat(int reg, int half) {
    return (reg & 3) + 8 * (reg >> 2) + 4 * half;
}

// ---------------- weights fp32 -> bf16 (Wq pre-scaled by 1/sqrt(Dh)=0.25) ----------------
__global__ __launch_bounds__(256) void cvtw_kernel(const float* __restrict__ w0, const float* __restrict__ w1,
                                                   const float* __restrict__ w2, const float* __restrict__ w3,
                                                   const float* __restrict__ w4, const float* __restrict__ w5,
                                                   u16* __restrict__ o) {
    const int sizes[6] = {16384, 16384, 16384, 16384, 32768, 32768};
    const int offs[6]  = {0, 16384, 32768, 49152, 65536, 98304};
    int y = blockIdx.y;
    int idx = blockIdx.x * 256 + threadIdx.x;
    const float* src = y == 0 ? w0 : y == 1 ? w1 : y == 2 ? w2 : y == 3 ? w3 : y == 4 ? w4 : w5;
    float scale = (y == 1) ? 0.25f : 1.0f;
    if (idx < sizes[y]) o[offs[y] + idx] = f2bf1(src[idx] * scale);
}

// ---------------- LayerNorm (last dim 128), one wave per row, bf16 out ----------------
__global__ __launch_bounds__(64) void ln_bf16_kernel(const float* __restrict__ x,
                                                     const float* __restrict__ g,
                                                     const float* __restrict__ b,
                                                     u16* __restrict__ y) {
    int row = blockIdx.x;
    int lane = threadIdx.x;
    const float* xr = x + (size_t)row * 128;
    float2 v = *(const float2*)(xr + lane * 2);
    float s = v.x + v.y;
    float sq = v.x * v.x + v.y * v.y;
    #pragma unroll
    for (int o = 32; o > 0; o >>= 1) { s += __shfl_xor(s, o); sq += __shfl_xor(sq, o); }
    float m = s * (1.f / 128.f);
    float var = sq * (1.f / 128.f) - m * m;
    float r = rsqrtf(fmaxf(var, 0.f) + 1e-5f);
    float2 gg = *(const float2*)(g + lane * 2);
    float2 bb = *(const float2*)(b + lane * 2);
    unsigned p = pk2((v.x - m) * r * gg.x + bb.x, (v.y - m) * r * gg.y + bb.y);
    *(unsigned*)(y + (size_t)row * 128 + lane * 2) = p;
}

// ---------------- GEMM: out[M,N] = A[M,K](bf16) @ W[N,K](bf16)^T ----------------
// MODE 0: bf16 out; 1: bf16 out, +bias, relu; 2: f32 out, +bias, +res; 3: f32 + bf16 dual, +bias
template<int K, int MODE>
__global__ __launch_bounds__(256) void gemm_bb(const u16* __restrict__ A, const u16* __restrict__ W,
                                               const float* __restrict__ bias,
                                               float* __restrict__ outf, u16* __restrict__ outb,
                                               const float* __restrict__ res, int ldo) {
    int t = threadIdx.x, w = t >> 6, lane = t & 63;
    int lm = lane & 31, half = lane >> 5;
    int row0 = blockIdx.x * 128 + w * 32;
    int col0 = blockIdx.y * 32;
    const u16* ap = A + (size_t)(row0 + lm) * K + half * 8;
    const u16* wp = W + (size_t)(col0 + lm) * K + half * 8;
    F16 acc;
    #pragma unroll
    for (int i = 0; i < 16; i++) acc.f[i] = 0.f;
    #pragma unroll
    for (int k0 = 0; k0 < K; k0 += 16) {
        B8 af, wf;
        af.q = *(const uint4*)(ap + k0);
        wf.q = *(const uint4*)(wp + k0);
        acc.v = __builtin_amdgcn_mfma_f32_32x32x16_bf16(af.v, wf.v, acc.v, 0, 0, 0);
    }
    int col = col0 + lm;
    float bv = (MODE != 0) ? bias[col] : 0.f;
    #pragma unroll
    for (int reg = 0; reg < 16; reg++) {
        int row = row0 + rowpat(reg, half);
        float v = acc.f[reg] + bv;
        if (MODE == 0) outb[(size_t)row * ldo + col] = f2bf1(v);
        if (MODE == 1) outb[(size_t)row * ldo + col] = f2bf1(fmaxf(v, 0.f));
        if (MODE == 2) outf[(size_t)row * ldo + col] = v + res[(size_t)row * ldo + col];
        if (MODE == 3) { outf[(size_t)row * ldo + col] = v; outb[(size_t)row * ldo + col] = f2bf1(v); }
    }
}

// ---------------- Fused edge-MLP + masked attention, flash-style, split-j ----------------
// grid(b=8, itile=32, z=2), block 512 = 8 waves, wave w = head w. Ti=Tj=32, 16 j-tiles per z.
__global__ __launch_bounds__(512, 4) void attn_kernel(
    const u16* __restrict__ Qm, const u16* __restrict__ Km, const u16* __restrict__ Vm,
    const float* __restrict__ ea, const int* __restrict__ adj,
    const float* __restrict__ We1, const float* __restrict__ be1,
    const float* __restrict__ We2, const float* __restrict__ be2,
    const float* __restrict__ eg, const float* __restrict__ eb,
    float* __restrict__ Opart, float* __restrict__ ml) {
    __shared__ u16 smK[32][132];        // bf16 K-tile [tj][f]
    __shared__ u16 smVt[128][36];       // bf16 V-tile transposed [f][tj]
    __shared__ float smBias[8480];      // [tj]*265 + h*33 + ti  (masked bias)

    int b = blockIdx.x, i0 = blockIdx.y * 32, z = blockIdx.z;
    int t = threadIdx.x, w = t >> 6;
    int lane = t & 63, lm = lane & 31, half = lane >> 5;

    // ---- per-lane constant fragments ----
    B8 qf, w1f, w2a, w2b;
    qf.q = *(const uint4*)(Qm + (size_t)(b * 1024 + i0 + lm) * 128 + w * 16 + half * 8);
    {   // A-frag We1*gamma: m = ch = lm, k = feat = half*8+j
        const float* wp = We1 + lm * 16 + half * 8;
        #pragma unroll
        for (int j = 0; j < 8; j++) w1f.s[j] = (short)f2bf(wp[j] * eg[half * 8 + j]);
    }
    {   // A-frags We2 (M rows 8..31 don't-care): m = h = lm&7
        int hs = lm & 7;
        #pragma unroll
        for (int j = 0; j < 8; j++) {
            w2a.s[j] = (short)f2bf(We2[hs * 32 + half * 8 + j]);
            w2b.s[j] = (short)f2bf(We2[hs * 32 + 16 + half * 8 + j]);
        }
    }
    // c1[ch] = sum_j We1[ch][j]*beta[j] + be1[ch] at D-row positions (MFMA1 C-seed)
    F16 c1s;
    #pragma unroll
    for (int reg = 0; reg < 16; reg++) {
        int ch = rowpat(reg, half);
        float sacc = be1[ch];
        const float* wr = We1 + ch * 16;
        #pragma unroll
        for (int j = 0; j < 16; j++) sacc += wr[j] * eb[j];
        c1s.f[reg] = sacc;
    }
    F16 c2s;   // MFMA2 C-seed: rows 0..7 = heads, carry be2
    #pragma unroll
    for (int i = 0; i < 16; i++) c2s.f[i] = 0.f;
    #pragma unroll
    for (int r = 0; r < 4; r++) c2s.f[r] = be2[r + 4 * half];

    F16 ou;
    #pragma unroll
    for (int i = 0; i < 16; i++) ou.f[i] = 0.f;
    float mrun = -3.0e38f, lrun = 0.f;

    #pragma unroll 1
    for (int nj = z * 16; nj < z * 16 + 16; nj++) {
        int j0 = nj * 32;
        __syncthreads();
        // ---- stage K and V^T (both already bf16) ----
        {
            int rr = t >> 4, fc = (t & 15) * 8;
            uint4 kq = *(const uint4*)(Km + (size_t)(b * 1024 + j0 + rr) * 128 + fc);
            uint2 ka; ka.x = kq.x; ka.y = kq.y;
            uint2 kb; kb.x = kq.z; kb.y = kq.w;
            *(uint2*)&smK[rr][fc] = ka;
            *(uint2*)&smK[rr][fc + 4] = kb;
            uint4 vq = *(const uint4*)(Vm + (size_t)(b * 1024 + j0 + rr) * 128 + fc);
            smVt[fc + 0][rr] = (u16)(vq.x & 0xffffu); smVt[fc + 1][rr] = (u16)(vq.x >> 16);
            smVt[fc + 2][rr] = (u16)(vq.y & 0xffffu); smVt[fc + 3][rr] = (u16)(vq.y >> 16);
            smVt[fc + 4][rr] = (u16)(vq.z & 0xffffu); smVt[fc + 5][rr] = (u16)(vq.z >> 16);
            smVt[fc + 6][rr] = (u16)(vq.w & 0xffffu); smVt[fc + 7][rr] = (u16)(vq.w >> 16);
        }
        // ---- edge MLP: 4 ti-rows per wave; lane edge = tj = lm ----
        for (int s4 = 0; s4 < 4; s4++) {
            int ti = w * 4 + s4;
            const float* ep = ea + ((size_t)(b * 1024 + i0 + ti) * 1024 + j0 + lm) * 16 + half * 8;
            float4 e0 = *(const float4*)ep, e1 = *(const float4*)(ep + 4);
            float sum = e0.x + e0.y + e0.z + e0.w + e1.x + e1.y + e1.z + e1.w;
            float sq = e0.x * e0.x + e0.y * e0.y + e0.z * e0.z + e0.w * e0.w
                     + e1.x * e1.x + e1.y * e1.y + e1.z * e1.z + e1.w * e1.w;
            sum += __shfl_xor(sum, 32); sq += __shfl_xor(sq, 32);
            float mn = sum * 0.0625f;
            float rs = rsqrtf(fmaxf(sq * 0.0625f - mn * mn, 0.f) + 1e-5f);
            float mr = mn * rs;
            B8 ef;   // B-frag eN^T: n = edge = lm, k = feat
            ef.u[0] = pk2(e0.x * rs - mr, e0.y * rs - mr);
            ef.u[1] = pk2(e0.z * rs - mr, e0.w * rs - mr);
            ef.u[2] = pk2(e1.x * rs - mr, e1.y * rs - mr);
            ef.u[3] = pk2(e1.z * rs - mr, e1.w * rs - mr);
            F16 h1; h1.v = __builtin_amdgcn_mfma_f32_32x32x16_bf16(w1f.v, ef.v, c1s.v, 0, 0, 0);
            // relu, pack, register cross-half exchange -> B-frags (k = ch), same mapping as P-exchange
            unsigned a01 = pk2(fmaxf(h1.f[0], 0.f),  fmaxf(h1.f[1], 0.f));
            unsigned a23 = pk2(fmaxf(h1.f[2], 0.f),  fmaxf(h1.f[3], 0.f));
            unsigned a45 = pk2(fmaxf(h1.f[4], 0.f),  fmaxf(h1.f[5], 0.f));
            unsigned a67 = pk2(fmaxf(h1.f[6], 0.f),  fmaxf(h1.f[7], 0.f));
            unsigned a89 = pk2(fmaxf(h1.f[8], 0.f),  fmaxf(h1.f[9], 0.f));
            unsigned aAB = pk2(fmaxf(h1.f[10], 0.f), fmaxf(h1.f[11], 0.f));
            unsigned aCD = pk2(fmaxf(h1.f[12], 0.f), fmaxf(h1.f[13], 0.f));
            unsigned aEF = pk2(fmaxf(h1.f[14], 0.f), fmaxf(h1.f[15], 0.f));
            unsigned x01 = __shfl_xor((int)a01, 32), x23 = __shfl_xor((int)a23, 32);
            unsigned x45 = __shfl_xor((int)a45, 32), x67 = __shfl_xor((int)a67, 32);
            unsigned x89 = __shfl_xor((int)a89, 32), xAB = __shfl_xor((int)aAB, 32);
            unsigned xCD = __shfl_xor((int)aCD, 32), xEF = __shfl_xor((int)aEF, 32);
            B8 hba, hbb;
            hba.u[0] = half ? x45 : a01;  hba.u[1] = half ? x67 : a23;
            hba.u[2] = half ? a45 : x01;  hba.u[3] = half ? a67 : x23;
            hbb.u[0] = half ? xCD : a89;  hbb.u[1] = half ? xEF : aAB;
            hbb.u[2] = half ? aCD : x89;  hbb.u[3] = half ? aEF : xAB;
            F16 b2; b2.v = __builtin_amdgcn_mfma_f32_32x32x16_bf16(w2a.v, hba.v, c2s.v, 0, 0, 0);
            b2.v = __builtin_amdgcn_mfma_f32_32x32x16_bf16(w2b.v, hbb.v, b2.v, 0, 0, 0);
            int aj = adj[(size_t)(b * 1024 + i0 + ti) * 1024 + j0 + lm];
            #pragma unroll
            for (int reg = 0; reg < 4; reg++) {   // D rows 0..7 = h, col = edge = tj
                float bvv = aj ? b2.f[reg] : -1.0e9f;
                smBias[lm * 265 + (reg + 4 * half) * 33 + ti] = bvv;
            }
        }
        __syncthreads();
        // ---- attention head w: S = K·Q^T + bias, col = ti = lm, rows = tj ----
        F16 sc;
        #pragma unroll
        for (int reg = 0; reg < 16; reg++) {
            int tj = rowpat(reg, half);
            sc.f[reg] = smBias[tj * 265 + w * 33 + lm];
        }
        B8 kf;   // A-frag K: m = tj = lm, k = d
        {
            const u16* kp2 = &smK[lm][w * 16 + half * 8];
            kf.d[0] = *(const uint2*)kp2; kf.d[1] = *(const uint2*)(kp2 + 4);
        }
        F16 s; s.v = __builtin_amdgcn_mfma_f32_32x32x16_bf16(kf.v, qf.v, sc.v, 0, 0, 0);
        float mx = -3.0e38f;
        #pragma unroll
        for (int reg = 0; reg < 16; reg++) {
            float vv = s.f[reg];
            vv = fmaxf(vv, 0.2f * vv);   // LeakyReLU(0.2)
            s.f[reg] = vv;
            mx = fmaxf(mx, vv);
        }
        mx = fmaxf(mx, __shfl_xor(mx, 32));
        float mnew = fmaxf(mrun, mx);
        float al = exp2f((mrun - mnew) * LOG2E);
        float psum = 0.f;
        #pragma unroll
        for (int reg = 0; reg < 16; reg++) {
            float p = exp2f((s.f[reg] - mnew) * LOG2E);
            s.f[reg] = p; psum += p;
        }
        lrun = lrun * al + psum; mrun = mnew;
        // pack P, build A-frags (k = tj) via cross-half exchange
        unsigned q0 = pk2(s.f[0], s.f[1]),   q0b = pk2(s.f[2], s.f[3]);
        unsigned q1 = pk2(s.f[4], s.f[5]),   q1b = pk2(s.f[6], s.f[7]);
        unsigned q2 = pk2(s.f[8], s.f[9]),   q2b = pk2(s.f[10], s.f[11]);
        unsigned q3 = pk2(s.f[12], s.f[13]), q3b = pk2(s.f[14], s.f[15]);
        unsigned x0 = __shfl_xor((int)q0, 32), x0b = __shfl_xor((int)q0b, 32);
        unsigned x1 = __shfl_xor((int)q1, 32), x1b = __shfl_xor((int)q1b, 32);
        unsigned x2 = __shfl_xor((int)q2, 32), x2b = __shfl_xor((int)q2b, 32);
        unsigned x3 = __shfl_xor((int)q3, 32), x3b = __shfl_xor((int)q3b, 32);
        B8 pfa, pfb;
        pfa.u[0] = half ? x1 : q0;  pfa.u[1] = half ? x1b : q0b;
        pfa.u[2] = half ? q1 : x0;  pfa.u[3] = half ? q1b : x0b;
        pfb.u[0] = half ? x3 : q2;  pfb.u[1] = half ? x3b : q2b;
        pfb.u[2] = half ? q3 : x2;  pfb.u[3] = half ? q3b : x2b;
        #pragma unroll
        for (int reg = 0; reg < 16; reg++) {
            float av = __shfl(al, rowpat(reg, half));
            ou.f[reg] *= av;
        }
        int dcol = lm & 15;
        const u16* vp2 = &smVt[w * 16 + dcol][half * 8];
        B8 vfa, vfb;   // B-frags V: n = d, k = tj
        vfa.d[0] = *(const uint2*)vp2;        vfa.d[1] = *(const uint2*)(vp2 + 4);
        vfb.d[0] = *(const uint2*)(vp2 + 16); vfb.d[1] = *(const uint2*)(vp2 + 20);
        ou.v = __builtin_amdgcn_mfma_f32_32x32x16_bf16(pfa.v, vfa.v, ou.v, 0, 0, 0);
        ou.v = __builtin_amdgcn_mfma_f32_32x32x16_bf16(pfb.v, vfb.v, ou.v, 0, 0, 0);
    }
    // ---- epilogue: write unnormalized partial O and (m, l) ----
    float ltot = lrun + __shfl_xor(lrun, 32);
    if (half == 0) {
        size_t mli = (((size_t)z * 8192 + b * 1024 + i0 + lm) * 8 + w) * 2;
        ml[mli] = mrun; ml[mli + 1] = ltot;
    }
    int dcol = lm & 15;
    #pragma unroll
    for (int reg = 0; reg < 16; reg++) {
        int row = rowpat(reg, half);
        if (lm < 16) {
            Opart[((size_t)z * 8192 + b * 1024 + i0 + row) * 128 + w * 16 + dcol] = ou.f[reg];
        }
    }
}

// ---------------- combine 2 flash partials + x_proj residual ----------------
__global__ __launch_bounds__(256) void combine_kernel(const float* __restrict__ O,
                                                      const float* __restrict__ ml,
                                                      const float* __restrict__ xp,
                                                      float* __restrict__ haw) {
    int t = threadIdx.x;
    int row = blockIdx.x * 2 + (t >> 7);
    int f = t & 127;
    int h = f >> 4;
    size_t base = (size_t)row * 128 + f;
    const float* mlp = ml + ((size_t)row * 8 + h) * 2;
    float m1 = mlp[0], l1 = mlp[1];
    float m2 = mlp[(size_t)8192 * 16], l2 = mlp[(size_t)8192 * 16 + 1];
    float m = fmaxf(m1, m2);
    float a1 = exp2f((m1 - m) * LOG2E), a2 = exp2f((m2 - m) * LOG2E);
    float l = l1 * a1 + l2 * a2;
    float o = O[base] * a1 + O[(size_t)8192 * 128 + base] * a2;
    haw[base] = o / l + xp[base];
}

extern "C" void kernel_launch(void* const* d_in, const int* in_sizes, int n_in,
                              void* d_out, int out_size, void* d_ws, size_t ws_size,
                              hipStream_t stream) {
    (void)in_sizes; (void)n_in; (void)out_size; (void)ws_size;
    const float* x    = (const float*)d_in[0];
    const int*   adj  = (const int*)d_in[1];
    const float* ea   = (const float*)d_in[2];
    const float* ln1g = (const float*)d_in[3];
    const float* ln1b = (const float*)d_in[4];
    const float* Wp   = (const float*)d_in[5];
    const float* bp   = (const float*)d_in[6];
    const float* eg   = (const float*)d_in[7];
    const float* eb   = (const float*)d_in[8];
    const float* We1  = (const float*)d_in[9];
    const float* be1  = (const float*)d_in[10];
    const float* We2  = (const float*)d_in[11];
    const float* be2  = (const float*)d_in[12];
    const float* Wq   = (const float*)d_in[13];
    const float* Wk   = (const float*)d_in[14];
    const float* Wv   = (const float*)d_in[15];
    const float* W1   = (const float*)d_in[16];
    const float* b1   = (const float*)d_in[17];
    const float* W2   = (const float*)d_in[18];
    const float* b2   = (const float*)d_in[19];
    const float* ln2g = (const float*)d_in[20];
    const float* ln2b = (const float*)d_in[21];
    float* out = (float*)d_out;
    char* wsb = (char*)d_ws;

    float* xprojF = (float*)(wsb);                         // 4 MB
    float* haw    = (float*)(wsb + ((size_t)4  << 20));    // 4 MB
    float* Opart  = (float*)(wsb + ((size_t)8  << 20));    // 8 MB
    float* mlbuf  = (float*)(wsb + ((size_t)16 << 20));    // 1 MB
    u16*   xnB    = (u16*)  (wsb + ((size_t)17 << 20));    // 2 MB
    u16*   xprojB = (u16*)  (wsb + ((size_t)19 << 20));    // 2 MB
    u16*   Qb     = (u16*)  (wsb + ((size_t)21 << 20));    // 2 MB
    u16*   Kb     = (u16*)  (wsb + ((size_t)23 << 20));    // 2 MB
    u16*   Vb     = (u16*)  (wsb + ((size_t)25 << 20));    // 2 MB
    u16*   hnB    = (u16*)  (wsb + ((size_t)27 << 20));    // 2 MB
    u16*   h1bB   = (u16*)  (wsb + ((size_t)29 << 20));    // 4 MB
    u16*   WB     = (u16*)  (wsb + ((size_t)33 << 20));    // 256 KB

    cvtw_kernel<<<dim3(128, 6), dim3(256), 0, stream>>>(Wp, Wq, Wk, Wv, W1, W2, WB);
    ln_bf16_kernel<<<dim3(8192), dim3(64), 0, stream>>>(x, ln1g, ln1b, xnB);
    gemm_bb<128, 3><<<dim3(64, 4), dim3(256), 0, stream>>>(xnB, WB, bp, xprojF, xprojB, nullptr, 128);
    gemm_bb<128, 0><<<dim3(64, 4), dim3(256), 0, stream>>>(xprojB, WB + 16384, nullptr, nullptr, Qb, nullptr, 128);
    gemm_bb<128, 0><<<dim3(64, 4), dim3(256), 0, stream>>>(xprojB, WB + 32768, nullptr, nullptr, Kb, nullptr, 128);
    gemm_bb<128, 0><<<dim3(64, 4), dim3(256), 0, stream>>>(xprojB, WB + 49152, nullptr, nullptr, Vb, nullptr, 128);
    attn_kernel<<<dim3(8, 32, 2), dim3(512), 0, stream>>>(Qb, Kb, Vb, ea, adj,
                                                          We1, be1, We2, be2, eg, eb, Opart, mlbuf);
    combine_kernel<<<dim3(4096), dim3(256), 0, stream>>>(Opart, mlbuf, xprojF, haw);
    ln_bf16_kernel<<<dim3(8192), dim3(64), 0, stream>>>(haw, ln2g, ln2b, hnB);
    gemm_bb<128, 1><<<dim3(64, 8), dim3(256), 0, stream>>>(hnB, WB + 65536, b1, nullptr, h1bB, nullptr, 256);
    gemm_bb<256, 2><<<dim3(64, 4), dim3(256), 0, stream>>>(h1bB, WB + 98304, b2, out, nullptr, haw, 128);
}